// Round 2
// baseline (424.753 us; speedup 1.0000x reference)
//
#include <hip/hip_runtime.h>
#include <math.h>
#include <stdint.h>

#define N_QUBITS 4
#define N_LAYERS 6
#define NW (N_LAYERS * N_QUBITS)

// POD 4-float vector (no C++ ctors -> safe across address spaces)
typedef float vfloat4 __attribute__((ext_vector_type(4)));

// ---------------------------------------------------------------------------
// Prep kernel (1 block): build W (16x16 complex) from the 24 RX gates + CNOT
// rings, form S_q = Re(W^dag Z_q W), contract to the 81-term multilinear table
//   out_q(x) = sum_{t in {I,Z,X}^4} C_q[t] * prod_p (1, cos x_p, sin x_p)[t_p]
// Layout: Ctab[t*4 + q]  (float4 per term t -> one load feeds all 4 outputs).
// (unchanged — single-variable experiment on the eval side)
// ---------------------------------------------------------------------------
__global__ __launch_bounds__(256) void qprep_kernel(
    const float* __restrict__ weights, float* __restrict__ Ctab)
{
    __shared__ float Wr[16][16];
    __shared__ float Wi[16][16];
    __shared__ float S[4][16][16];
    __shared__ float wc[NW], ws[NW];
    const int tid = threadIdx.x;
    if (tid < NW) {
        float t = weights[tid] * 0.5f;
        wc[tid] = __cosf(t);
        ws[tid] = __sinf(t);
    }
    __syncthreads();

    // Phase 1: threads 0..15 build column `tid` of W
    if (tid < 16) {
        float re[16], im[16];
#pragma unroll
        for (int k = 0; k < 16; ++k) { re[k] = (k == tid) ? 1.f : 0.f; im[k] = 0.f; }
#pragma unroll 1
        for (int l = 0; l < N_LAYERS; ++l) {
#pragma unroll
            for (int q = 0; q < 4; ++q) {
                const float ct = wc[l * 4 + q], sn = ws[l * 4 + q];
                const int mask = 8 >> q;
#pragma unroll
                for (int idx = 0; idx < 16; ++idx) {
                    if (idx & mask) continue;
                    const int j = idx | mask;
                    float r0 = re[idx], u0 = im[idx], r1 = re[j], u1 = im[j];
                    re[idx] = ct * r0 + sn * u1; im[idx] = ct * u0 - sn * r1;
                    re[j]   = ct * r1 + sn * u0; im[j]   = ct * u1 - sn * r0;
                }
            }
#pragma unroll
            for (int q = 0; q < 4; ++q) {
                const int cm = 8 >> q, tm = 8 >> ((q + 1) & 3);
#pragma unroll
                for (int idx = 0; idx < 16; ++idx) {
                    if ((idx & cm) && !(idx & tm)) {
                        const int j = idx | tm;
                        float t0 = re[idx]; re[idx] = re[j]; re[j] = t0;
                        float t1 = im[idx]; im[idx] = im[j]; im[j] = t1;
                    }
                }
            }
        }
#pragma unroll
        for (int k = 0; k < 16; ++k) { Wr[k][tid] = re[k]; Wi[k][tid] = im[k]; }
    }
    __syncthreads();

    // Phase 2: thread (i,j): S_q[i][j] = sum_k z_q(k) Re(W[k,i] conj(W[k,j]))
    {
        const int i = tid >> 4, j = tid & 15;
        float acc0 = 0.f, acc1 = 0.f, acc2 = 0.f, acc3 = 0.f;
#pragma unroll
        for (int k = 0; k < 16; ++k) {
            const float prod = Wr[k][i] * Wr[k][j] + Wi[k][i] * Wi[k][j];
            acc0 += (k & 8) ? -prod : prod;
            acc1 += (k & 4) ? -prod : prod;
            acc2 += (k & 2) ? -prod : prod;
            acc3 += (k & 1) ? -prod : prod;
        }
        S[0][i][j] = acc0; S[1][i][j] = acc1; S[2][i][j] = acc2; S[3][i][j] = acc3;
    }
    __syncthreads();

    // Phase 3: C_q[t] = (1/16) sum_i (-1)^popc(i&zm) S_q[i][i^xm]
    if (tid < 81) {
        const int t1 = tid / 27, t2 = (tid / 9) % 3, t3 = (tid / 3) % 3, t4 = tid % 3;
        int zm = 0, xm = 0;
        if (t1 == 1) zm |= 8; else if (t1 == 2) xm |= 8;
        if (t2 == 1) zm |= 4; else if (t2 == 2) xm |= 4;
        if (t3 == 1) zm |= 2; else if (t3 == 2) xm |= 2;
        if (t4 == 1) zm |= 1; else if (t4 == 2) xm |= 1;
#pragma unroll
        for (int q = 0; q < 4; ++q) {
            float acc = 0.f;
#pragma unroll
            for (int i = 0; i < 16; ++i) {
                const float v = S[q][i][i ^ xm];
                acc += (__popc(i & zm) & 1) ? -v : v;
            }
            Ctab[tid * 4 + q] = acc * 0.0625f;   // float4-per-term layout
        }
    }
}

// ---------------------------------------------------------------------------
// Main kernel. KEY CHANGE vs R10: 4 samples per thread (block tile = 1024
// samples, grid 4096 -> 1024). The 81 uniform ds_read_b128 table reads per
// wave are fixed overhead; amortizing them over 4x the FMA work drops the
// aggregate LDS-pipe time 4x (16 waves/CU x 81 x ~3cy ~= 1.6 us, hidden
// under VALU) and amortizes loop/launch overhead. All 4 x-loads issue
// before the staging barrier so HBM latency is covered once.
// Register budget: u9/w9 x4 = 72 + acc x4 = 16 + transient t = 16
// ~= 120 VGPR -> fits __launch_bounds__(256,4) (<=128 VGPR) without spill.
// ---------------------------------------------------------------------------
#define SPT 4   // samples per thread

__global__ __launch_bounds__(256, 4) void qeval_kernel(
    const float* __restrict__ x, const float* __restrict__ Ctab,
    float* __restrict__ out, int B)
{
    __shared__ vfloat4 Cs[81];

    const int tid = threadIdx.x;
    const int base = blockIdx.x * (256 * SPT) + tid;

    // Issue the per-thread x loads first (hide under the staging barrier).
    float4 xv[SPT];
#pragma unroll
    for (int s = 0; s < SPT; ++s) {
        int b = base + s * 256;
        b = (b < B) ? b : (B - 1);           // clamp for load safety
        xv[s] = reinterpret_cast<const float4*>(x)[b];
    }

    // Stage coefficient table into LDS (one float4 per thread, 81 threads).
    if (tid < 81) {
        Cs[tid] = reinterpret_cast<const vfloat4*>(Ctab)[tid];
    }
    __syncthreads();

    float u9[SPT][9], w9[SPT][9];
#pragma unroll
    for (int s = 0; s < SPT; ++s) {
        const float c0 = __cosf(xv[s].x), s0 = __sinf(xv[s].x);
        const float c1 = __cosf(xv[s].y), s1 = __sinf(xv[s].y);
        const float c2 = __cosf(xv[s].z), s2 = __sinf(xv[s].z);
        const float c3 = __cosf(xv[s].w), s3 = __sinf(xv[s].w);
        u9[s][0] = 1.f;  u9[s][1] = c1;      u9[s][2] = s1;
        u9[s][3] = c0;   u9[s][4] = c0 * c1; u9[s][5] = c0 * s1;
        u9[s][6] = s0;   u9[s][7] = s0 * c1; u9[s][8] = s0 * s1;
        w9[s][0] = 1.f;  w9[s][1] = c3;      w9[s][2] = s3;
        w9[s][3] = c2;   w9[s][4] = c2 * c3; w9[s][5] = c2 * s3;
        w9[s][6] = s2;   w9[s][7] = s2 * c3; w9[s][8] = s2 * s3;
    }

    float4 o[SPT];
#pragma unroll
    for (int s = 0; s < SPT; ++s) o[s] = make_float4(0.f, 0.f, 0.f, 0.f);

#pragma unroll
    for (int i = 0; i < 9; ++i) {
        float4 t[SPT];
#pragma unroll
        for (int s = 0; s < SPT; ++s) t[s] = make_float4(0.f, 0.f, 0.f, 0.f);
#pragma unroll
        for (int j = 0; j < 9; ++j) {
            const vfloat4 c = Cs[i * 9 + j];   // uniform addr -> LDS broadcast
#pragma unroll
            for (int s = 0; s < SPT; ++s) {
                const float w = w9[s][j];
                t[s].x = fmaf(c.x, w, t[s].x);
                t[s].y = fmaf(c.y, w, t[s].y);
                t[s].z = fmaf(c.z, w, t[s].z);
                t[s].w = fmaf(c.w, w, t[s].w);
            }
        }
#pragma unroll
        for (int s = 0; s < SPT; ++s) {
            const float u = u9[s][i];
            o[s].x = fmaf(t[s].x, u, o[s].x);
            o[s].y = fmaf(t[s].y, u, o[s].y);
            o[s].z = fmaf(t[s].z, u, o[s].z);
            o[s].w = fmaf(t[s].w, u, o[s].w);
        }
    }

#pragma unroll
    for (int s = 0; s < SPT; ++s) {
        const int b = base + s * 256;
        if (b < B) reinterpret_cast<float4*>(out)[b] = o[s];
    }
}

extern "C" void kernel_launch(void* const* d_in, const int* in_sizes, int n_in,
                              void* d_out, int out_size, void* d_ws, size_t ws_size,
                              hipStream_t stream) {
    const float* x = (const float*)d_in[0];
    const float* weights = (const float*)d_in[1];
    float* out = (float*)d_out;
    float* Ctab = (float*)d_ws;   // 324 floats, float4-per-term
    const int B = in_sizes[0] / 4;

    qprep_kernel<<<1, 256, 0, stream>>>(weights, Ctab);

    const int tile = 256 * SPT;
    const int grid = (B + tile - 1) / tile;
    qeval_kernel<<<grid, 256, 0, stream>>>(x, Ctab, out, B);
}

// Round 4
// 92.906 us; speedup vs baseline: 4.5718x; 4.5718x over previous
//
#include <hip/hip_runtime.h>
#include <math.h>
#include <stdint.h>

#define N_QUBITS 4
#define N_LAYERS 6
#define NW (N_LAYERS * N_QUBITS)

// POD 4-float vector (no C++ ctors -> safe across address spaces)
typedef float vfloat4 __attribute__((ext_vector_type(4)));

// ---------------------------------------------------------------------------
// Prep kernel (1 block): build W (16x16 complex) from the 24 RX gates + CNOT
// rings, form S_q = Re(W^dag Z_q W), contract to the 81-term multilinear table
//   out_q(x) = sum_{t in {I,Z,X}^4} C_q[t] * prod_p (1, cos x_p, sin x_p)[t_p]
// Layout: Ctab[t*4 + q]  (float4 per term t -> one load feeds all 4 outputs).
// (unchanged)
// ---------------------------------------------------------------------------
__global__ __launch_bounds__(256) void qprep_kernel(
    const float* __restrict__ weights, float* __restrict__ Ctab)
{
    __shared__ float Wr[16][16];
    __shared__ float Wi[16][16];
    __shared__ float S[4][16][16];
    __shared__ float wc[NW], ws[NW];
    const int tid = threadIdx.x;
    if (tid < NW) {
        float t = weights[tid] * 0.5f;
        wc[tid] = __cosf(t);
        ws[tid] = __sinf(t);
    }
    __syncthreads();

    // Phase 1: threads 0..15 build column `tid` of W
    if (tid < 16) {
        float re[16], im[16];
#pragma unroll
        for (int k = 0; k < 16; ++k) { re[k] = (k == tid) ? 1.f : 0.f; im[k] = 0.f; }
#pragma unroll 1
        for (int l = 0; l < N_LAYERS; ++l) {
#pragma unroll
            for (int q = 0; q < 4; ++q) {
                const float ct = wc[l * 4 + q], sn = ws[l * 4 + q];
                const int mask = 8 >> q;
#pragma unroll
                for (int idx = 0; idx < 16; ++idx) {
                    if (idx & mask) continue;
                    const int j = idx | mask;
                    float r0 = re[idx], u0 = im[idx], r1 = re[j], u1 = im[j];
                    re[idx] = ct * r0 + sn * u1; im[idx] = ct * u0 - sn * r1;
                    re[j]   = ct * r1 + sn * u0; im[j]   = ct * u1 - sn * r0;
                }
            }
#pragma unroll
            for (int q = 0; q < 4; ++q) {
                const int cm = 8 >> q, tm = 8 >> ((q + 1) & 3);
#pragma unroll
                for (int idx = 0; idx < 16; ++idx) {
                    if ((idx & cm) && !(idx & tm)) {
                        const int j = idx | tm;
                        float t0 = re[idx]; re[idx] = re[j]; re[j] = t0;
                        float t1 = im[idx]; im[idx] = im[j]; im[j] = t1;
                    }
                }
            }
        }
#pragma unroll
        for (int k = 0; k < 16; ++k) { Wr[k][tid] = re[k]; Wi[k][tid] = im[k]; }
    }
    __syncthreads();

    // Phase 2: thread (i,j): S_q[i][j] = sum_k z_q(k) Re(W[k,i] conj(W[k,j]))
    {
        const int i = tid >> 4, j = tid & 15;
        float acc0 = 0.f, acc1 = 0.f, acc2 = 0.f, acc3 = 0.f;
#pragma unroll
        for (int k = 0; k < 16; ++k) {
            const float prod = Wr[k][i] * Wr[k][j] + Wi[k][i] * Wi[k][j];
            acc0 += (k & 8) ? -prod : prod;
            acc1 += (k & 4) ? -prod : prod;
            acc2 += (k & 2) ? -prod : prod;
            acc3 += (k & 1) ? -prod : prod;
        }
        S[0][i][j] = acc0; S[1][i][j] = acc1; S[2][i][j] = acc2; S[3][i][j] = acc3;
    }
    __syncthreads();

    // Phase 3: C_q[t] = (1/16) sum_i (-1)^popc(i&zm) S_q[i][i^xm]
    if (tid < 81) {
        const int t1 = tid / 27, t2 = (tid / 9) % 3, t3 = (tid / 3) % 3, t4 = tid % 3;
        int zm = 0, xm = 0;
        if (t1 == 1) zm |= 8; else if (t1 == 2) xm |= 8;
        if (t2 == 1) zm |= 4; else if (t2 == 2) xm |= 4;
        if (t3 == 1) zm |= 2; else if (t3 == 2) xm |= 2;
        if (t4 == 1) zm |= 1; else if (t4 == 2) xm |= 1;
#pragma unroll
        for (int q = 0; q < 4; ++q) {
            float acc = 0.f;
#pragma unroll
            for (int i = 0; i < 16; ++i) {
                const float v = S[q][i][i ^ xm];
                acc += (__popc(i & zm) & 1) ? -v : v;
            }
            Ctab[tid * 4 + q] = acc * 0.0625f;   // float4-per-term layout
        }
    }
}

// ---------------------------------------------------------------------------
// Main kernel. R13 = R12 resubmit after infra failure, de-risked: back to
// __cosf/__sinf (validated in R8-R10; __sincosf's pointer-out locals were
// the only unvalidated primitive). Single variable vs R10: SPT=2
// samples/thread WITHOUT any min-waves launch-bounds hint.
// R11's __launch_bounds__(256,4) capped the allocator at 64 VGPR and spilled
// ~120 floats of state to scratch (FETCH_SIZE 690 MB, VALUBusy 1.5%,
// 356 us). SPT=2 needs ~75-90 VGPR; uncapped, it stays in registers. The 81
// uniform ds_read_b128 broadcast reads per wave now feed 2x the FMA work,
// halving aggregate LDS-pipe time and amortizing setup/launch overhead.
// ---------------------------------------------------------------------------
#define SPT 2   // samples per thread

__global__ __launch_bounds__(256) void qeval_kernel(
    const float* __restrict__ x, const float* __restrict__ Ctab,
    float* __restrict__ out, int B)
{
    __shared__ vfloat4 Cs[81];

    const int tid = threadIdx.x;
    const int base = blockIdx.x * (256 * SPT) + tid;

    // Issue the per-thread x loads first (hide under the staging barrier).
    float4 xv0, xv1;
    {
        int b0 = base;            b0 = (b0 < B) ? b0 : (B - 1);
        int b1 = base + 256;      b1 = (b1 < B) ? b1 : (B - 1);
        xv0 = reinterpret_cast<const float4*>(x)[b0];
        xv1 = reinterpret_cast<const float4*>(x)[b1];
    }

    // Stage coefficient table into LDS (one float4 per thread, 81 threads).
    if (tid < 81) {
        Cs[tid] = reinterpret_cast<const vfloat4*>(Ctab)[tid];
    }
    __syncthreads();

    // Per-sample basis vectors.
    float uA[9], wA[9], uB[9], wB[9];
    {
        const float c0 = __cosf(xv0.x), s0 = __sinf(xv0.x);
        const float c1 = __cosf(xv0.y), s1 = __sinf(xv0.y);
        const float c2 = __cosf(xv0.z), s2 = __sinf(xv0.z);
        const float c3 = __cosf(xv0.w), s3 = __sinf(xv0.w);
        uA[0] = 1.f;  uA[1] = c1;      uA[2] = s1;
        uA[3] = c0;   uA[4] = c0 * c1; uA[5] = c0 * s1;
        uA[6] = s0;   uA[7] = s0 * c1; uA[8] = s0 * s1;
        wA[0] = 1.f;  wA[1] = c3;      wA[2] = s3;
        wA[3] = c2;   wA[4] = c2 * c3; wA[5] = c2 * s3;
        wA[6] = s2;   wA[7] = s2 * c3; wA[8] = s2 * s3;
    }
    {
        const float c0 = __cosf(xv1.x), s0 = __sinf(xv1.x);
        const float c1 = __cosf(xv1.y), s1 = __sinf(xv1.y);
        const float c2 = __cosf(xv1.z), s2 = __sinf(xv1.z);
        const float c3 = __cosf(xv1.w), s3 = __sinf(xv1.w);
        uB[0] = 1.f;  uB[1] = c1;      uB[2] = s1;
        uB[3] = c0;   uB[4] = c0 * c1; uB[5] = c0 * s1;
        uB[6] = s0;   uB[7] = s0 * c1; uB[8] = s0 * s1;
        wB[0] = 1.f;  wB[1] = c3;      wB[2] = s3;
        wB[3] = c2;   wB[4] = c2 * c3; wB[5] = c2 * s3;
        wB[6] = s2;   wB[7] = s2 * c3; wB[8] = s2 * s3;
    }

    float4 oA = make_float4(0.f, 0.f, 0.f, 0.f);
    float4 oB = make_float4(0.f, 0.f, 0.f, 0.f);

#pragma unroll
    for (int i = 0; i < 9; ++i) {
        float4 tA = make_float4(0.f, 0.f, 0.f, 0.f);
        float4 tB = make_float4(0.f, 0.f, 0.f, 0.f);
#pragma unroll
        for (int j = 0; j < 9; ++j) {
            const vfloat4 c = Cs[i * 9 + j];   // uniform addr -> LDS broadcast
            const float wa = wA[j], wb = wB[j];
            tA.x = fmaf(c.x, wa, tA.x);
            tA.y = fmaf(c.y, wa, tA.y);
            tA.z = fmaf(c.z, wa, tA.z);
            tA.w = fmaf(c.w, wa, tA.w);
            tB.x = fmaf(c.x, wb, tB.x);
            tB.y = fmaf(c.y, wb, tB.y);
            tB.z = fmaf(c.z, wb, tB.z);
            tB.w = fmaf(c.w, wb, tB.w);
        }
        const float ua = uA[i], ub = uB[i];
        oA.x = fmaf(tA.x, ua, oA.x);
        oA.y = fmaf(tA.y, ua, oA.y);
        oA.z = fmaf(tA.z, ua, oA.z);
        oA.w = fmaf(tA.w, ua, oA.w);
        oB.x = fmaf(tB.x, ub, oB.x);
        oB.y = fmaf(tB.y, ub, oB.y);
        oB.z = fmaf(tB.z, ub, oB.z);
        oB.w = fmaf(tB.w, ub, oB.w);
    }

    {
        const int b0 = base;
        const int b1 = base + 256;
        if (b0 < B) reinterpret_cast<float4*>(out)[b0] = oA;
        if (b1 < B) reinterpret_cast<float4*>(out)[b1] = oB;
    }
}

extern "C" void kernel_launch(void* const* d_in, const int* in_sizes, int n_in,
                              void* d_out, int out_size, void* d_ws, size_t ws_size,
                              hipStream_t stream) {
    const float* x = (const float*)d_in[0];
    const float* weights = (const float*)d_in[1];
    float* out = (float*)d_out;
    float* Ctab = (float*)d_ws;   // 324 floats, float4-per-term
    const int B = in_sizes[0] / 4;

    qprep_kernel<<<1, 256, 0, stream>>>(weights, Ctab);

    const int tile = 256 * SPT;
    const int grid = (B + tile - 1) / tile;
    qeval_kernel<<<grid, 256, 0, stream>>>(x, Ctab, out, B);
}